// Round 4
// baseline (72.982 us; speedup 1.0000x reference)
//
#include <hip/hip_runtime.h>

#define D   512
#define HW  196   // 14*14
#define NS  8     // K-split count for the small GEMMs

// Workspace layout (floats):
//   p_part   [NS][128][512]   @ 0        (524288)
//   t12_part [NS][128][1024]  @ 524288   (1048576)
//   w_part   [NS][128][512]   @ 1572864  (524288)
// total ~8.4 MB << ws_size

// ---------------------------------------------------------------------------
// Stage 1 (384 blocks): blocks 0..127 -> p partials, 128..383 -> t12 partials.
// ---------------------------------------------------------------------------
__global__ void k_stage1(const float* __restrict__ m_prev, const float* __restrict__ W_m,
                         const float* __restrict__ b_m, const float* __restrict__ c,
                         const float* __restrict__ W_attn, const float* __restrict__ W_merge,
                         float* __restrict__ p_part, float* __restrict__ t12_part) {
    const int bx = blockIdx.x;
    const int t  = threadIdx.x;
    __shared__ float xs[16][64];

    if (bx < 128) {                       // ---- p: grid (jt2, bt8, kt8) ----
        const int jt = bx & 1, bt = (bx >> 1) & 7, kt = bx >> 4;
        const int j  = jt * 256 + t;
        const int b0 = bt * 16;
        const int k0 = kt * 64;
        for (int i = t; i < 16 * 64; i += 256)
            xs[i >> 6][i & 63] = m_prev[(b0 + (i >> 6)) * D + k0 + (i & 63)];
        __syncthreads();
        float acc[16];
        #pragma unroll
        for (int bb = 0; bb < 16; ++bb) acc[bb] = 0.f;
        for (int kk = 0; kk < 64; ++kk) {
            float wv = W_m[(k0 + kk) * D + j];        // coalesced across lanes
            #pragma unroll
            for (int bb = 0; bb < 16; ++bb) acc[bb] += xs[bb][kk] * wv;
        }
        const float bias = (kt == 0) ? b_m[j] : 0.f;  // bias folded into split 0
        #pragma unroll
        for (int bb = 0; bb < 16; ++bb)
            p_part[((size_t)kt * 128 + b0 + bb) * D + j] = acc[bb] + bias;
    } else {                              // ---- t12: grid (kkt4, bt8, jt8) ----
        const int i2 = bx - 128;
        const int kkt = i2 & 3, bt = (i2 >> 2) & 7, jt = i2 >> 5;
        const int kk = kkt * 256 + t;     // 0..1023
        const int b0 = bt * 16;
        const int j0 = jt * 64;
        for (int i = t; i < 16 * 64; i += 256) {
            int bb = i >> 6, jj = i & 63;
            xs[bb][jj] = c[(b0 + bb) * D + j0 + jj] * W_attn[j0 + jj];
        }
        __syncthreads();
        float acc[16];
        #pragma unroll
        for (int bb = 0; bb < 16; ++bb) acc[bb] = 0.f;
        const float4* wrow = (const float4*)&W_merge[(size_t)kk * D + j0];
        for (int q = 0; q < 16; ++q) {
            float4 w4 = wrow[q];
            #pragma unroll
            for (int bb = 0; bb < 16; ++bb)
                acc[bb] += xs[bb][4*q+0] * w4.x + xs[bb][4*q+1] * w4.y
                         + xs[bb][4*q+2] * w4.z + xs[bb][4*q+3] * w4.w;
        }
        #pragma unroll
        for (int bb = 0; bb < 16; ++bb)
            t12_part[((size_t)jt * 128 + b0 + bb) * 1024 + kk] = acc[bb];
    }
}

// ---------------------------------------------------------------------------
// Stage 2 (128 blocks): w partials only (beta moved into k_c).
//   r[b,k] = (Σ_s p_part)(Σ_s t1_part);  w_part[kt][b][kp] = Σ_k W_kb[kp][k] r
// ---------------------------------------------------------------------------
__global__ void k_stage2(const float* __restrict__ p_part, const float* __restrict__ t12_part,
                         const float* __restrict__ W_kb, float* __restrict__ w_part) {
    const int bx = blockIdx.x;
    const int t  = threadIdx.x;
    __shared__ float rs[16][64];

    const int kpt = bx & 1, bt = (bx >> 1) & 7, kt = bx >> 4;
    const int kp = kpt * 256 + t;
    const int b0 = bt * 16;
    const int k0 = kt * 64;
    for (int i = t; i < 16 * 64; i += 256) {
        int bb = i >> 6, kk = i & 63;
        int b = b0 + bb, k = k0 + kk;
        float pv = 0.f, tv = 0.f;
        #pragma unroll
        for (int s = 0; s < NS; ++s) {
            pv += p_part[((size_t)s * 128 + b) * D + k];
            tv += t12_part[((size_t)s * 128 + b) * 1024 + k];   // t1 = cols [0,512)
        }
        rs[bb][kk] = pv * tv;
    }
    __syncthreads();
    float acc[16];
    #pragma unroll
    for (int bb = 0; bb < 16; ++bb) acc[bb] = 0.f;
    const float4* wrow = (const float4*)&W_kb[(size_t)kp * D + k0];
    for (int q = 0; q < 16; ++q) {
        float4 w4 = wrow[q];
        #pragma unroll
        for (int bb = 0; bb < 16; ++bb)
            acc[bb] += rs[bb][4*q+0] * w4.x + rs[bb][4*q+1] * w4.y
                     + rs[bb][4*q+2] * w4.z + rs[bb][4*q+3] * w4.w;
    }
    #pragma unroll
    for (int bb = 0; bb < 16; ++bb) {
        float extra = 0.f;
        if (kt == 0) {                // fold t2 into split 0
            #pragma unroll
            for (int s = 0; s < NS; ++s)
                extra += t12_part[((size_t)s * 128 + b0 + bb) * 1024 + 512 + kp];
        }
        w_part[((size_t)kt * 128 + b0 + bb) * D + kp] = acc[bb] + extra;
    }
}

// ---------------------------------------------------------------------------
// k_c (128 blocks x 1024 threads): per-batch fused finale.
//   threads <512: stage w_s (fold NS partials); threads >=512: beta reduce.
//   pass 1: mv[hw] = Σ_k KB[b,k,hw]*w_s[k] + beta     (HBM pass, mv in LDS)
//   pass 2: out[b,k] = Σ_hw KB[b,k,hw]*mv[hw]          (L2-hot re-read)
// ---------------------------------------------------------------------------
__global__ __launch_bounds__(1024) void k_c(const float* __restrict__ KB,
                                            const float* __restrict__ w_part,
                                            const float* __restrict__ p_part,
                                            const float* __restrict__ t12_part,
                                            const float* __restrict__ c,
                                            const float* __restrict__ W_attn,
                                            const float* __restrict__ b_merge,
                                            const float* __restrict__ b_kb,
                                            const float* __restrict__ b_attn,
                                            float* __restrict__ out) {
    const int b = blockIdx.x;
    const int t = threadIdx.x;
    __shared__ float w_s[512];
    __shared__ float part[4][200];
    __shared__ float mv_s[200];
    __shared__ float outp[2][512];
    __shared__ float redB[8];

    if (t < 512) {                        // stage w
        float s = 0.f;
        #pragma unroll
        for (int q = 0; q < NS; ++q) s += w_part[((size_t)q * 128 + b) * D + t];
        w_s[t] = s;
    } else {                              // beta contributions, j = t-512
        const int j = t - 512;
        float pv = 0.f, tv = 0.f;
        #pragma unroll
        for (int q = 0; q < NS; ++q) {
            pv += p_part[((size_t)q * 128 + b) * D + j];
            tv += t12_part[((size_t)q * 128 + b) * 1024 + j];
        }
        float u = c[b * D + j] * W_attn[j];
        float contrib = b_merge[j] * u + b_kb[j] * (pv * tv);
        #pragma unroll
        for (int off = 32; off; off >>= 1) contrib += __shfl_down(contrib, off, 64);
        if ((t & 63) == 0) redB[(t >> 6) - 8] = contrib;
    }
    __syncthreads();

    // ---- pass 1: HBM read of KB[b] (401 KB), coalesced over hw ----
    {
        const int ks = t >> 8, hw = t & 255;
        if (hw < HW) {
            const float* kbp = KB + (size_t)b * D * HW + (size_t)ks * 128 * HW + hw;
            float acc = 0.f;
            #pragma unroll 16
            for (int k = 0; k < 128; ++k) acc += kbp[(size_t)k * HW] * w_s[ks * 128 + k];
            part[ks][hw] = acc;
        }
    }
    __syncthreads();
    if (t < HW) {
        float beta = redB[0] + redB[1] + redB[2] + redB[3]
                   + redB[4] + redB[5] + redB[6] + redB[7] + b_attn[0];
        mv_s[t] = part[0][t] + part[1][t] + part[2][t] + part[3][t] + beta;
    }
    __syncthreads();

    // ---- pass 2: L2-hot re-read, per-lane float4 rows ----
    {
        const int k = t & 511, half = t >> 9;
        const float4* row = (const float4*)(KB + (size_t)b * D * HW + (size_t)k * HW);
        float acc = 0.f;
        const int h0 = half ? 25 : 0, h1 = half ? 49 : 25;
        for (int h4 = h0; h4 < h1; ++h4) {
            float4 v = row[h4];
            acc += v.x * mv_s[4*h4+0] + v.y * mv_s[4*h4+1]
                 + v.z * mv_s[4*h4+2] + v.w * mv_s[4*h4+3];
        }
        outp[half][k] = acc;
    }
    __syncthreads();
    if (t < 512) out[(size_t)b * D + t] = outp[0][t] + outp[1][t];
}

// ---------------------------------------------------------------------------
extern "C" void kernel_launch(void* const* d_in, const int* in_sizes, int n_in,
                              void* d_out, int out_size, void* d_ws, size_t ws_size,
                              hipStream_t stream) {
    const float* m_prev  = (const float*)d_in[0];
    const float* KB      = (const float*)d_in[1];
    const float* c_i     = (const float*)d_in[2];
    const float* W_m     = (const float*)d_in[3];
    const float* b_m     = (const float*)d_in[4];
    const float* W_kb    = (const float*)d_in[5];
    const float* b_kb    = (const float*)d_in[6];
    const float* W_merge = (const float*)d_in[7];
    const float* b_merge = (const float*)d_in[8];
    const float* W_attn  = (const float*)d_in[9];
    const float* b_attn  = (const float*)d_in[10];
    float* out = (float*)d_out;

    float* ws       = (float*)d_ws;
    float* p_part   = ws;               // [NS][128][512]
    float* t12_part = ws + 524288;      // [NS][128][1024]
    float* w_part   = ws + 1572864;     // [NS][128][512]

    k_stage1<<<384, 256, 0, stream>>>(m_prev, W_m, b_m, c_i, W_attn, W_merge,
                                      p_part, t12_part);
    k_stage2<<<128, 256, 0, stream>>>(p_part, t12_part, W_kb, w_part);
    k_c     <<<128, 1024, 0, stream>>>(KB, w_part, p_part, t12_part, c_i, W_attn,
                                       b_merge, b_kb, b_attn, out);
}

// Round 5
// 51.127 us; speedup vs baseline: 1.4275x; 1.4275x over previous
//
#include <hip/hip_runtime.h>

#define D   512
#define HW  196   // 14*14
#define NS  8     // K-split count for the small GEMMs
#define MS  16    // k-split count for the KB passes

// Workspace layout (floats):
//   p_part   [NS][128][512]   @ 0        (524288)
//   t12_part [NS][128][1024]  @ 524288   (1048576)
//   w_part   [NS][128][512]   @ 1572864  (524288)
//   beta     [128]            @ 2097152
//   mvp      [128][MS][196]   @ 2097280  (401408)

// ---------------------------------------------------------------------------
// Stage 1 (384 blocks): blocks 0..127 -> p partials, 128..383 -> t12 partials.
// ---------------------------------------------------------------------------
__global__ void k_stage1(const float* __restrict__ m_prev, const float* __restrict__ W_m,
                         const float* __restrict__ b_m, const float* __restrict__ c,
                         const float* __restrict__ W_attn, const float* __restrict__ W_merge,
                         float* __restrict__ p_part, float* __restrict__ t12_part) {
    const int bx = blockIdx.x;
    const int t  = threadIdx.x;
    __shared__ float xs[16][64];

    if (bx < 128) {                       // ---- p: grid (jt2, bt8, kt8) ----
        const int jt = bx & 1, bt = (bx >> 1) & 7, kt = bx >> 4;
        const int j  = jt * 256 + t;
        const int b0 = bt * 16;
        const int k0 = kt * 64;
        for (int i = t; i < 16 * 64; i += 256)
            xs[i >> 6][i & 63] = m_prev[(b0 + (i >> 6)) * D + k0 + (i & 63)];
        __syncthreads();
        float acc[16];
        #pragma unroll
        for (int bb = 0; bb < 16; ++bb) acc[bb] = 0.f;
        for (int kk = 0; kk < 64; ++kk) {
            float wv = W_m[(k0 + kk) * D + j];        // coalesced across lanes
            #pragma unroll
            for (int bb = 0; bb < 16; ++bb) acc[bb] += xs[bb][kk] * wv;
        }
        const float bias = (kt == 0) ? b_m[j] : 0.f;  // bias folded into split 0
        #pragma unroll
        for (int bb = 0; bb < 16; ++bb)
            p_part[((size_t)kt * 128 + b0 + bb) * D + j] = acc[bb] + bias;
    } else {                              // ---- t12: grid (kkt4, bt8, jt8) ----
        const int i2 = bx - 128;
        const int kkt = i2 & 3, bt = (i2 >> 2) & 7, jt = i2 >> 5;
        const int kk = kkt * 256 + t;     // 0..1023
        const int b0 = bt * 16;
        const int j0 = jt * 64;
        for (int i = t; i < 16 * 64; i += 256) {
            int bb = i >> 6, jj = i & 63;
            xs[bb][jj] = c[(b0 + bb) * D + j0 + jj] * W_attn[j0 + jj];
        }
        __syncthreads();
        float acc[16];
        #pragma unroll
        for (int bb = 0; bb < 16; ++bb) acc[bb] = 0.f;
        const float4* wrow = (const float4*)&W_merge[(size_t)kk * D + j0];
        for (int q = 0; q < 16; ++q) {
            float4 w4 = wrow[q];
            #pragma unroll
            for (int bb = 0; bb < 16; ++bb)
                acc[bb] += xs[bb][4*q+0] * w4.x + xs[bb][4*q+1] * w4.y
                         + xs[bb][4*q+2] * w4.z + xs[bb][4*q+3] * w4.w;
        }
        #pragma unroll
        for (int bb = 0; bb < 16; ++bb)
            t12_part[((size_t)jt * 128 + b0 + bb) * 1024 + kk] = acc[bb];
    }
}

// ---------------------------------------------------------------------------
// Stage 2 (256 blocks): blocks 0..127 -> w partials, 128..255 -> beta.
// ---------------------------------------------------------------------------
__global__ void k_stage2(const float* __restrict__ p_part, const float* __restrict__ t12_part,
                         const float* __restrict__ W_kb, const float* __restrict__ c,
                         const float* __restrict__ W_attn, const float* __restrict__ b_merge,
                         const float* __restrict__ b_kb, const float* __restrict__ b_attn,
                         float* __restrict__ w_part, float* __restrict__ beta) {
    const int bx = blockIdx.x;
    const int t  = threadIdx.x;
    __shared__ float rs[16][64];

    if (bx < 128) {                       // ---- w: grid (kpt2, bt8, kt8) ----
        const int kpt = bx & 1, bt = (bx >> 1) & 7, kt = bx >> 4;
        const int kp = kpt * 256 + t;
        const int b0 = bt * 16;
        const int k0 = kt * 64;
        for (int i = t; i < 16 * 64; i += 256) {
            int bb = i >> 6, kk = i & 63;
            int b = b0 + bb, k = k0 + kk;
            float pv = 0.f, tv = 0.f;
            #pragma unroll
            for (int s = 0; s < NS; ++s) {
                pv += p_part[((size_t)s * 128 + b) * D + k];
                tv += t12_part[((size_t)s * 128 + b) * 1024 + k];   // t1 = cols [0,512)
            }
            rs[bb][kk] = pv * tv;
        }
        __syncthreads();
        float acc[16];
        #pragma unroll
        for (int bb = 0; bb < 16; ++bb) acc[bb] = 0.f;
        const float4* wrow = (const float4*)&W_kb[(size_t)kp * D + k0];
        for (int q = 0; q < 16; ++q) {
            float4 w4 = wrow[q];
            #pragma unroll
            for (int bb = 0; bb < 16; ++bb)
                acc[bb] += rs[bb][4*q+0] * w4.x + rs[bb][4*q+1] * w4.y
                         + rs[bb][4*q+2] * w4.z + rs[bb][4*q+3] * w4.w;
        }
        #pragma unroll
        for (int bb = 0; bb < 16; ++bb) {
            float extra = 0.f;
            if (kt == 0) {                // fold t2 into split 0
                #pragma unroll
                for (int s = 0; s < NS; ++s)
                    extra += t12_part[((size_t)s * 128 + b0 + bb) * 1024 + 512 + kp];
            }
            w_part[((size_t)kt * 128 + b0 + bb) * D + kp] = acc[bb] + extra;
        }
    } else {                              // ---- beta ----
        const int b = bx - 128;
        float sum = 0.f;
        for (int j = t; j < D; j += 256) {
            float pv = 0.f, tv = 0.f;
            #pragma unroll
            for (int s = 0; s < NS; ++s) {
                pv += p_part[((size_t)s * 128 + b) * D + j];
                tv += t12_part[((size_t)s * 128 + b) * 1024 + j];
            }
            float u = c[b * D + j] * W_attn[j];
            sum += b_merge[j] * u + b_kb[j] * (pv * tv);
        }
        #pragma unroll
        for (int off = 32; off; off >>= 1) sum += __shfl_down(sum, off, 64);
        __shared__ float red[4];
        if ((t & 63) == 0) red[t >> 6] = sum;
        __syncthreads();
        if (t == 0) beta[b] = red[0] + red[1] + red[2] + red[3] + b_attn[0];
    }
}

// ---------------------------------------------------------------------------
// K_MV: 2048 blocks (b, ks in [0,MS)), 256 threads. k-chunk of 32.
//   mvp[b][ks][hw] = sum_{k in chunk} KB[b,k,hw] * w[b,k]
// hw-lane mapping -> 256B coalesced wave loads; 32-deep chains; 8 blk/CU.
// ---------------------------------------------------------------------------
__global__ void k_mv(const float* __restrict__ KB, const float* __restrict__ w_part,
                     float* __restrict__ mvp) {
    const int b  = blockIdx.x >> 4;
    const int ks = blockIdx.x & (MS - 1);
    const int t  = threadIdx.x;
    __shared__ float wl[32];
    if (t < 32) {
        float s = 0.f;
        #pragma unroll
        for (int q = 0; q < NS; ++q)
            s += w_part[((size_t)q * 128 + b) * D + ks * 32 + t];
        wl[t] = s;
    }
    __syncthreads();
    if (t < HW) {
        const float* kbp = KB + (size_t)b * D * HW + (size_t)ks * 32 * HW + t;
        float acc = 0.f;
        #pragma unroll
        for (int k = 0; k < 32; ++k) acc += kbp[(size_t)k * HW] * wl[k];
        mvp[((size_t)b * MS + ks) * HW + t] = acc;
    }
}

// ---------------------------------------------------------------------------
// K_MNEW: 2048 blocks (b, kt in [0,16)), 256 threads = 4 waves x 8 rows.
// Fold mvp (+beta) into LDS, then one wave per (b,k) row: 49 lanes load the
// contiguous 784B row as float4 (coalesced), dot vs mv4, butterfly-reduce.
// ---------------------------------------------------------------------------
__global__ void k_mnew(const float* __restrict__ KB, const float* __restrict__ mvp,
                       const float* __restrict__ beta, float* __restrict__ out) {
    const int b  = blockIdx.x >> 4;
    const int kt = blockIdx.x & 15;
    const int t  = threadIdx.x;
    const int wave = t >> 6, lane = t & 63;
    __shared__ float4 mv4_s[49];

    if (t < HW) {
        float s = beta[b];
        #pragma unroll
        for (int q = 0; q < MS; ++q)
            s += mvp[((size_t)b * MS + q) * HW + t];
        ((float*)mv4_s)[t] = s;
    }
    __syncthreads();

    const float4 m4 = (lane < 49) ? mv4_s[lane] : make_float4(0.f, 0.f, 0.f, 0.f);
    #pragma unroll
    for (int i = 0; i < 8; ++i) {
        const int k = kt * 32 + wave * 8 + i;
        float p = 0.f;
        if (lane < 49) {
            float4 v = ((const float4*)(KB + ((size_t)b * D + k) * HW))[lane];
            p = v.x * m4.x + v.y * m4.y + v.z * m4.z + v.w * m4.w;
        }
        #pragma unroll
        for (int off = 32; off; off >>= 1) p += __shfl_xor(p, off, 64);
        if (lane == 0) out[(size_t)b * D + k] = p;
    }
}

// ---------------------------------------------------------------------------
extern "C" void kernel_launch(void* const* d_in, const int* in_sizes, int n_in,
                              void* d_out, int out_size, void* d_ws, size_t ws_size,
                              hipStream_t stream) {
    const float* m_prev  = (const float*)d_in[0];
    const float* KB      = (const float*)d_in[1];
    const float* c_i     = (const float*)d_in[2];
    const float* W_m     = (const float*)d_in[3];
    const float* b_m     = (const float*)d_in[4];
    const float* W_kb    = (const float*)d_in[5];
    const float* b_kb    = (const float*)d_in[6];
    const float* W_merge = (const float*)d_in[7];
    const float* b_merge = (const float*)d_in[8];
    const float* W_attn  = (const float*)d_in[9];
    const float* b_attn  = (const float*)d_in[10];
    float* out = (float*)d_out;

    float* ws       = (float*)d_ws;
    float* p_part   = ws;               // [NS][128][512]
    float* t12_part = ws + 524288;      // [NS][128][1024]
    float* w_part   = ws + 1572864;     // [NS][128][512]
    float* beta     = ws + 2097152;     // [128]
    float* mvp      = ws + 2097280;     // [128][MS][196]

    k_stage1<<<384, 256, 0, stream>>>(m_prev, W_m, b_m, c_i, W_attn, W_merge,
                                      p_part, t12_part);
    k_stage2<<<256, 256, 0, stream>>>(p_part, t12_part, W_kb, c_i, W_attn,
                                      b_merge, b_kb, b_attn, w_part, beta);
    k_mv  <<<2048, 256, 0, stream>>>(KB, w_part, mvp);
    k_mnew<<<2048, 256, 0, stream>>>(KB, mvp, beta, out);
}